// Round 1
// baseline (606.806 us; speedup 1.0000x reference)
//
#include <hip/hip_runtime.h>
#include <cstdint>
#include <cstddef>

// ---------------- problem constants ----------------
#define DD 1024          // feature dim (= K = N per GEMM)
#define TT 8192          // sequence length
#define BB 4             // batch
#define MM (BB*TT)       // 32768 rows
#define NCHUNK 64        // scan chunks over T
#define CLEN 128         // chunk length (NCHUNK*CLEN == TT)
#define EPS 1e-5f

typedef __attribute__((ext_vector_type(8))) short bf16x8;
typedef __attribute__((ext_vector_type(4))) float f32x4;

// ---------------- bf16 helpers (bit-level, RNE) ----------------
__device__ __forceinline__ float bf2f(unsigned short b) {
  union { unsigned int u; float f; } c; c.u = ((unsigned int)b) << 16; return c.f;
}
__device__ __forceinline__ unsigned short f2bf(float f) {
  union { float f; unsigned int u; } c; c.f = f;
  unsigned int lsb = (c.u >> 16) & 1u;
  c.u += 0x7fffu + lsb;
  return (unsigned short)(c.u >> 16);
}

// ---------------- async global->LDS (16B per lane) ----------------
__device__ __forceinline__ void gload16(const void* gsrc, void* ldst) {
  __builtin_amdgcn_global_load_lds(
      (const __attribute__((address_space(1))) unsigned int*)gsrc,
      (__attribute__((address_space(3))) unsigned int*)ldst, 16, 0, 0);
}

// Stage a 128x32 bf16 tile (rows row0..row0+127, k-cols k0..k0+31) from a
// row-major (rows, 1024) bf16 matrix into LDS laid out [128][32] linear.
// 256 threads: 2 passes x 16B/lane; LDS dest offset == tid*16 + p*4096,
// which is exactly wave-uniform-base + lane*16 (m104 constraint satisfied).
__device__ __forceinline__ void stage_tile(const unsigned short* __restrict__ g,
                                           size_t row0, int k0,
                                           unsigned short* lds, int tid) {
#pragma unroll
  for (int p = 0; p < 2; ++p) {
    int row  = (tid >> 2) + p * 64;
    int colB = (tid & 3) * 16;
    const char* src = (const char*)g + (row0 + (size_t)row) * (size_t)(DD * 2)
                      + (size_t)k0 * 2 + colB;
    char* dst = (char*)lds + p * 4096 + tid * 16;
    gload16(src, dst);
  }
}

// ---------------- kernel 1: cast weights to bf16 ----------------
__global__ __launch_bounds__(256) void cast_weights(
    const float* __restrict__ wg, const float* __restrict__ wv,
    const float* __restrict__ wo,
    unsigned short* __restrict__ owg, unsigned short* __restrict__ owv,
    unsigned short* __restrict__ owo) {
  int i = blockIdx.x * 256 + threadIdx.x;   // over float4 units; 3*262144 total
  const float* src; unsigned short* dst; int off;
  if (i < 262144)       { src = wg; dst = owg; off = i; }
  else if (i < 524288)  { src = wv; dst = owv; off = i - 262144; }
  else                  { src = wo; dst = owo; off = i - 524288; }
  float4 v = ((const float4*)src)[off];
  ushort4 o;
  o.x = f2bf(v.x); o.y = f2bf(v.y); o.z = f2bf(v.z); o.w = f2bf(v.w);
  ((ushort4*)dst)[off] = o;
}

// ---------------- kernel 2: LayerNorm -> bf16 ----------------
__global__ __launch_bounds__(256) void ln_kernel(
    const float* __restrict__ x, const float* __restrict__ gamma,
    const float* __restrict__ beta, unsigned short* __restrict__ normed) {
  size_t row = blockIdx.x;
  int tid = threadIdx.x, lane = tid & 63, wid = tid >> 6;
  float4 v = ((const float4*)(x + row * DD))[tid];
  float s = v.x + v.y + v.z + v.w;
  float q = v.x * v.x + v.y * v.y + v.z * v.z + v.w * v.w;
#pragma unroll
  for (int off = 32; off; off >>= 1) {
    s += __shfl_down(s, off);
    q += __shfl_down(q, off);
  }
  __shared__ float rs[4], rq[4];
  if (lane == 0) { rs[wid] = s; rq[wid] = q; }
  __syncthreads();
  float ts = rs[0] + rs[1] + rs[2] + rs[3];
  float tq = rq[0] + rq[1] + rq[2] + rq[3];
  float mu  = ts * (1.0f / DD);
  float var = tq * (1.0f / DD) - mu * mu;
  float rstd = rsqrtf(var + EPS);
  float4 gm = ((const float4*)gamma)[tid];
  float4 bt = ((const float4*)beta)[tid];
  ushort4 o;
  o.x = f2bf((v.x - mu) * rstd * gm.x + bt.x);
  o.y = f2bf((v.y - mu) * rstd * gm.y + bt.y);
  o.z = f2bf((v.z - mu) * rstd * gm.z + bt.z);
  o.w = f2bf((v.w - mu) * rstd * gm.w + bt.w);
  ((ushort4*)normed)[row * (DD / 4) + tid] = o;
}

// ---------------- kernel 3: fused gate/value GEMM -> u ----------------
// u[m,e] = (2*sigmoid(normed@Wg^T + bg) - 1) * (normed@Wv^T + bv)
__global__ __launch_bounds__(256) void gemm_gv(
    const unsigned short* __restrict__ normed,
    const unsigned short* __restrict__ wg, const unsigned short* __restrict__ wv,
    const float* __restrict__ bg, const float* __restrict__ bv,
    unsigned short* __restrict__ u) {
  __shared__ unsigned short As[128 * 32];
  __shared__ unsigned short Bgs[128 * 32];
  __shared__ unsigned short Bvs[128 * 32];
  int tid = threadIdx.x, lane = tid & 63, wid = tid >> 6;
  int wm = wid >> 1, wn = wid & 1;
  size_t m0 = (size_t)blockIdx.x * 128;
  int n0 = blockIdx.y * 128;

  f32x4 accg[4][4], accv[4][4];
#pragma unroll
  for (int a = 0; a < 4; ++a)
#pragma unroll
    for (int b = 0; b < 4; ++b) {
      accg[a][b] = (f32x4){0.f, 0.f, 0.f, 0.f};
      accv[a][b] = (f32x4){0.f, 0.f, 0.f, 0.f};
    }

  int r = lane & 15, kb = (lane >> 4) * 8;
  for (int kt = 0; kt < DD / 32; ++kt) {
    int k0 = kt * 32;
    stage_tile(normed, m0, k0, As, tid);
    stage_tile(wg, (size_t)n0, k0, Bgs, tid);
    stage_tile(wv, (size_t)n0, k0, Bvs, tid);
    __syncthreads();
    bf16x8 af[4];
#pragma unroll
    for (int mi = 0; mi < 4; ++mi)
      af[mi] = *(const bf16x8*)&As[(wm * 64 + mi * 16 + r) * 32 + kb];
#pragma unroll
    for (int ni = 0; ni < 4; ++ni) {
      bf16x8 bgf = *(const bf16x8*)&Bgs[(wn * 64 + ni * 16 + r) * 32 + kb];
      bf16x8 bvf = *(const bf16x8*)&Bvs[(wn * 64 + ni * 16 + r) * 32 + kb];
#pragma unroll
      for (int mi = 0; mi < 4; ++mi) {
        accg[mi][ni] = __builtin_amdgcn_mfma_f32_16x16x32_bf16(af[mi], bgf, accg[mi][ni], 0, 0, 0);
        accv[mi][ni] = __builtin_amdgcn_mfma_f32_16x16x32_bf16(af[mi], bvf, accv[mi][ni], 0, 0, 0);
      }
    }
    __syncthreads();
  }

  // epilogue: C/D layout col=lane&15, row=(lane>>4)*4+j  [m89/m91 verified]
#pragma unroll
  for (int mi = 0; mi < 4; ++mi)
#pragma unroll
    for (int ni = 0; ni < 4; ++ni) {
      int e = n0 + wn * 64 + ni * 16 + (lane & 15);
      size_t rbase = m0 + wm * 64 + mi * 16 + (lane >> 4) * 4;
      float bgv = bg[e], bvv = bv[e];
#pragma unroll
      for (int j = 0; j < 4; ++j) {
        float gp = accg[mi][ni][j] + bgv;
        float vp = accv[mi][ni][j] + bvv;
        float sg = 1.0f / (1.0f + __expf(-gp));
        float uu = (2.0f * sg - 1.0f) * vp;
        u[(rbase + j) * DD + e] = f2bf(uu);
      }
    }
}

// ---------------- kernel 4: per-chunk partial sums ----------------
__global__ __launch_bounds__(256) void scan_partial(
    const unsigned short* __restrict__ u, float* __restrict__ sums) {
  int b = blockIdx.x >> 6, chunk = blockIdx.x & 63;
  int tid = threadIdx.x, e0 = tid * 4;
  float a0 = 0.f, a1 = 0.f, a2 = 0.f, a3 = 0.f;
  size_t base = ((size_t)b * TT + (size_t)chunk * CLEN) * DD + e0;
#pragma unroll 4
  for (int i = 0; i < CLEN; ++i) {
    ushort4 w = *(const ushort4*)(u + base + (size_t)i * DD);
    a0 += bf2f(w.x); a1 += bf2f(w.y); a2 += bf2f(w.z); a3 += bf2f(w.w);
  }
  float4 rr; rr.x = a0; rr.y = a1; rr.z = a2; rr.w = a3;
  *(float4*)(sums + ((size_t)(b * NCHUNK + chunk)) * DD + e0) = rr;
}

// ---------------- kernel 5: exclusive scan over chunk sums (in place) ----------------
__global__ __launch_bounds__(256) void scan_chunks(float* __restrict__ sums) {
  int b = blockIdx.x >> 2;
  int e = (blockIdx.x & 3) * 256 + threadIdx.x;
  float carry = 0.f;
  for (int c = 0; c < NCHUNK; ++c) {
    size_t idx = ((size_t)(b * NCHUNK + c)) * DD + e;
    float t = sums[idx];
    sums[idx] = carry;
    carry += t;
  }
}

// ---------------- kernel 6: chunk-local scan + decay, in place ----------------
__global__ __launch_bounds__(256) void scan_final(
    unsigned short* __restrict__ u, const float* __restrict__ sums,
    const float* __restrict__ log_decay) {
  int b = blockIdx.x >> 6, chunk = blockIdx.x & 63;
  int tid = threadIdx.x, e0 = tid * 4;
  float alpha = log1pf(__expf(log_decay[0]));   // softplus
  float4 c = *(const float4*)(sums + ((size_t)(b * NCHUNK + chunk)) * DD + e0);
  size_t base = ((size_t)b * TT + (size_t)chunk * CLEN) * DD + e0;
#pragma unroll 4
  for (int i = 0; i < CLEN; ++i) {
    int t = chunk * CLEN + i;
    float dec = __expf(-alpha * (float)t);
    ushort4 w = *(const ushort4*)(u + base + (size_t)i * DD);
    c.x += bf2f(w.x); c.y += bf2f(w.y); c.z += bf2f(w.z); c.w += bf2f(w.w);
    ushort4 o;
    o.x = f2bf(c.x * dec); o.y = f2bf(c.y * dec);
    o.z = f2bf(c.z * dec); o.w = f2bf(c.w * dec);
    *(ushort4*)(u + base + (size_t)i * DD) = o;
  }
}

// ---------------- kernel 7: output GEMM + residual ----------------
// out[m,e] = x[m,e] + bo[e] + sum_d c[m,d]*Wo[e,d]
__global__ __launch_bounds__(256) void gemm_out(
    const unsigned short* __restrict__ cmat, const unsigned short* __restrict__ wo,
    const float* __restrict__ bo, const float* __restrict__ x,
    float* __restrict__ out) {
  __shared__ unsigned short As[128 * 32];
  __shared__ unsigned short Bs[128 * 32];
  int tid = threadIdx.x, lane = tid & 63, wid = tid >> 6;
  int wm = wid >> 1, wn = wid & 1;
  size_t m0 = (size_t)blockIdx.x * 128;
  int n0 = blockIdx.y * 128;

  f32x4 acc[4][4];
#pragma unroll
  for (int a = 0; a < 4; ++a)
#pragma unroll
    for (int b = 0; b < 4; ++b) acc[a][b] = (f32x4){0.f, 0.f, 0.f, 0.f};

  int r = lane & 15, kb = (lane >> 4) * 8;
  for (int kt = 0; kt < DD / 32; ++kt) {
    int k0 = kt * 32;
    stage_tile(cmat, m0, k0, As, tid);
    stage_tile(wo, (size_t)n0, k0, Bs, tid);
    __syncthreads();
    bf16x8 af[4];
#pragma unroll
    for (int mi = 0; mi < 4; ++mi)
      af[mi] = *(const bf16x8*)&As[(wm * 64 + mi * 16 + r) * 32 + kb];
#pragma unroll
    for (int ni = 0; ni < 4; ++ni) {
      bf16x8 bf = *(const bf16x8*)&Bs[(wn * 64 + ni * 16 + r) * 32 + kb];
#pragma unroll
      for (int mi = 0; mi < 4; ++mi)
        acc[mi][ni] = __builtin_amdgcn_mfma_f32_16x16x32_bf16(af[mi], bf, acc[mi][ni], 0, 0, 0);
    }
    __syncthreads();
  }

#pragma unroll
  for (int mi = 0; mi < 4; ++mi)
#pragma unroll
    for (int ni = 0; ni < 4; ++ni) {
      int e = n0 + wn * 64 + ni * 16 + (lane & 15);
      size_t rbase = m0 + wm * 64 + mi * 16 + (lane >> 4) * 4;
      float bov = bo[e];
#pragma unroll
      for (int j = 0; j < 4; ++j) {
        size_t idx = (rbase + j) * DD + e;
        out[idx] = x[idx] + bov + acc[mi][ni][j];
      }
    }
}

// ---------------- launch ----------------
extern "C" void kernel_launch(void* const* d_in, const int* in_sizes, int n_in,
                              void* d_out, int out_size, void* d_ws, size_t ws_size,
                              hipStream_t stream) {
  const float* x     = (const float*)d_in[0];
  const float* gamma = (const float*)d_in[1];
  const float* beta  = (const float*)d_in[2];
  const float* Wg    = (const float*)d_in[3];
  const float* bg    = (const float*)d_in[4];
  const float* Wv    = (const float*)d_in[5];
  const float* bv    = (const float*)d_in[6];
  const float* Wo    = (const float*)d_in[7];
  const float* bo    = (const float*)d_in[8];
  const float* ldcy  = (const float*)d_in[9];
  float* out = (float*)d_out;

  char* ws = (char*)d_ws;
  // layout: normed bf16 (64MiB) | u/c bf16 (64MiB) | Wg,Wv,Wo bf16 (3x2MiB) | sums f32 (1MiB)
  unsigned short* normed = (unsigned short*)ws;
  unsigned short* u      = (unsigned short*)(ws + (size_t)67108864);
  unsigned short* wgb    = (unsigned short*)(ws + (size_t)134217728);
  unsigned short* wvb    = wgb + 1048576;
  unsigned short* wob    = wvb + 1048576;
  float* sums            = (float*)(ws + (size_t)134217728 + (size_t)3 * 2097152);

  cast_weights<<<3072, 256, 0, stream>>>(Wg, Wv, Wo, wgb, wvb, wob);
  ln_kernel<<<MM, 256, 0, stream>>>(x, gamma, beta, normed);
  gemm_gv<<<dim3(MM / 128, DD / 128), 256, 0, stream>>>(normed, wgb, wvb, bg, bv, u);
  scan_partial<<<BB * NCHUNK, 256, 0, stream>>>(u, sums);
  scan_chunks<<<BB * (DD / 256), 256, 0, stream>>>(sums);
  scan_final<<<BB * NCHUNK, 256, 0, stream>>>(u, sums, ldcy);
  gemm_out<<<dim3(MM / 128, DD / 128), 256, 0, stream>>>(u, wob, bo, x, out);
}

// Round 2
// 425.271 us; speedup vs baseline: 1.4269x; 1.4269x over previous
//
#include <hip/hip_runtime.h>
#include <cstdint>
#include <cstddef>

// ---------------- problem constants ----------------
#define DD 1024          // feature dim (= K = N per GEMM)
#define TT 8192          // sequence length
#define BB 4             // batch
#define MM (BB*TT)       // 32768 rows
#define NCHUNK 64        // scan chunks over T
#define CLEN 128         // chunk length (NCHUNK*CLEN == TT)
#define EPS 1e-5f

typedef __attribute__((ext_vector_type(8))) short bf16x8;
typedef __attribute__((ext_vector_type(4))) float f32x4;

// ---------------- bf16 helpers (bit-level, RNE) ----------------
__device__ __forceinline__ float bf2f(unsigned short b) {
  union { unsigned int u; float f; } c; c.u = ((unsigned int)b) << 16; return c.f;
}
__device__ __forceinline__ unsigned short f2bf(float f) {
  union { float f; unsigned int u; } c; c.f = f;
  unsigned int lsb = (c.u >> 16) & 1u;
  c.u += 0x7fffu + lsb;
  return (unsigned short)(c.u >> 16);
}

// ---------------- async global->LDS (16B per lane) ----------------
__device__ __forceinline__ void gload16(const void* gsrc, void* ldst) {
  __builtin_amdgcn_global_load_lds(
      (const __attribute__((address_space(1))) unsigned int*)gsrc,
      (__attribute__((address_space(3))) unsigned int*)ldst, 16, 0, 0);
}

// Stage a 128x32 bf16 tile with 512 threads: exactly one 16B gload per thread.
// LDS linear [128][32]; dest = tid*16 (wave-uniform base + lane*16, m104-safe).
__device__ __forceinline__ void stage512(const unsigned short* __restrict__ g,
                                         size_t row0, int k0,
                                         unsigned short* lds, int tid) {
  int row  = tid >> 2;            // 0..127
  int colB = (tid & 3) * 16;      // byte offset within 64B row
  const char* src = (const char*)g + (row0 + (size_t)row) * (size_t)(DD * 2)
                    + (size_t)k0 * 2 + colB;
  gload16(src, (char*)lds + tid * 16);
}

// Stage a 128x32 tile with 256 threads (2 passes) — for gemm_out.
__device__ __forceinline__ void stage256(const unsigned short* __restrict__ g,
                                         size_t row0, int k0,
                                         unsigned short* lds, int tid) {
#pragma unroll
  for (int p = 0; p < 2; ++p) {
    int row  = (tid >> 2) + p * 64;
    int colB = (tid & 3) * 16;
    const char* src = (const char*)g + (row0 + (size_t)row) * (size_t)(DD * 2)
                      + (size_t)k0 * 2 + colB;
    gload16(src, (char*)lds + p * 4096 + tid * 16);
  }
}

// ---------------- kernel 1: cast weights to bf16 ----------------
__global__ __launch_bounds__(256) void cast_weights(
    const float* __restrict__ wg, const float* __restrict__ wv,
    const float* __restrict__ wo,
    unsigned short* __restrict__ owg, unsigned short* __restrict__ owv,
    unsigned short* __restrict__ owo) {
  int i = blockIdx.x * 256 + threadIdx.x;   // over float4 units; 3*262144 total
  const float* src; unsigned short* dst; int off;
  if (i < 262144)       { src = wg; dst = owg; off = i; }
  else if (i < 524288)  { src = wv; dst = owv; off = i - 262144; }
  else                  { src = wo; dst = owo; off = i - 524288; }
  float4 v = ((const float4*)src)[off];
  ushort4 o;
  o.x = f2bf(v.x); o.y = f2bf(v.y); o.z = f2bf(v.z); o.w = f2bf(v.w);
  ((ushort4*)dst)[off] = o;
}

// ---------------- kernel 2: LayerNorm -> bf16 ----------------
__global__ __launch_bounds__(256) void ln_kernel(
    const float* __restrict__ x, const float* __restrict__ gamma,
    const float* __restrict__ beta, unsigned short* __restrict__ normed) {
  size_t row = blockIdx.x;
  int tid = threadIdx.x, lane = tid & 63, wid = tid >> 6;
  float4 v = ((const float4*)(x + row * DD))[tid];
  float s = v.x + v.y + v.z + v.w;
  float q = v.x * v.x + v.y * v.y + v.z * v.z + v.w * v.w;
#pragma unroll
  for (int off = 32; off; off >>= 1) {
    s += __shfl_down(s, off);
    q += __shfl_down(q, off);
  }
  __shared__ float rs[4], rq[4];
  if (lane == 0) { rs[wid] = s; rq[wid] = q; }
  __syncthreads();
  float ts = rs[0] + rs[1] + rs[2] + rs[3];
  float tq = rq[0] + rq[1] + rq[2] + rq[3];
  float mu  = ts * (1.0f / DD);
  float var = tq * (1.0f / DD) - mu * mu;
  float rstd = rsqrtf(var + EPS);
  float4 gm = ((const float4*)gamma)[tid];
  float4 bt = ((const float4*)beta)[tid];
  ushort4 o;
  o.x = f2bf((v.x - mu) * rstd * gm.x + bt.x);
  o.y = f2bf((v.y - mu) * rstd * gm.y + bt.y);
  o.z = f2bf((v.z - mu) * rstd * gm.z + bt.z);
  o.w = f2bf((v.w - mu) * rstd * gm.w + bt.w);
  ((ushort4*)normed)[row * (DD / 4) + tid] = o;
}

// ---------------- kernel 3: fused gate/value GEMM -> u ----------------
// 8 waves / 512 threads per 128x128 tile. Wave (wm,wn) owns rows wm*32..+32,
// cols wn*64..+64 of BOTH outputs: acc = 2x4 f32x4 per output = 64 regs total.
// u[m,e] = (2*sigmoid(normed@Wg^T + bg) - 1) * (normed@Wv^T + bv)
__global__ __launch_bounds__(512) void gemm_gv(
    const unsigned short* __restrict__ normed,
    const unsigned short* __restrict__ wg, const unsigned short* __restrict__ wv,
    const float* __restrict__ bg, const float* __restrict__ bv,
    unsigned short* __restrict__ u) {
  __shared__ unsigned short As[128 * 32];
  __shared__ unsigned short Bgs[128 * 32];
  __shared__ unsigned short Bvs[128 * 32];
  int tid = threadIdx.x, lane = tid & 63, wid = tid >> 6;  // wid 0..7
  int wm = wid & 3, wn = wid >> 2;   // 4 row-groups x 2 col-groups
  size_t m0 = (size_t)blockIdx.x * 128;
  int n0 = blockIdx.y * 128;

  f32x4 accg[2][4], accv[2][4];
#pragma unroll
  for (int a = 0; a < 2; ++a)
#pragma unroll
    for (int b = 0; b < 4; ++b) {
      accg[a][b] = (f32x4){0.f, 0.f, 0.f, 0.f};
      accv[a][b] = (f32x4){0.f, 0.f, 0.f, 0.f};
    }

  int r = lane & 15, kb = (lane >> 4) * 8;
  for (int kt = 0; kt < DD / 32; ++kt) {
    int k0 = kt * 32;
    stage512(normed, m0, k0, As, tid);
    stage512(wg, (size_t)n0, k0, Bgs, tid);
    stage512(wv, (size_t)n0, k0, Bvs, tid);
    __syncthreads();
    bf16x8 af[2];
#pragma unroll
    for (int mi = 0; mi < 2; ++mi)
      af[mi] = *(const bf16x8*)&As[(wm * 32 + mi * 16 + r) * 32 + kb];
#pragma unroll
    for (int ni = 0; ni < 4; ++ni) {
      bf16x8 bgf = *(const bf16x8*)&Bgs[(wn * 64 + ni * 16 + r) * 32 + kb];
      bf16x8 bvf = *(const bf16x8*)&Bvs[(wn * 64 + ni * 16 + r) * 32 + kb];
#pragma unroll
      for (int mi = 0; mi < 2; ++mi) {
        accg[mi][ni] = __builtin_amdgcn_mfma_f32_16x16x32_bf16(af[mi], bgf, accg[mi][ni], 0, 0, 0);
        accv[mi][ni] = __builtin_amdgcn_mfma_f32_16x16x32_bf16(af[mi], bvf, accv[mi][ni], 0, 0, 0);
      }
    }
    __syncthreads();
  }

  // epilogue: C/D layout col=lane&15, row=(lane>>4)*4+j  [m89/m91 verified]
#pragma unroll
  for (int mi = 0; mi < 2; ++mi)
#pragma unroll
    for (int ni = 0; ni < 4; ++ni) {
      int e = n0 + wn * 64 + ni * 16 + (lane & 15);
      size_t rbase = m0 + wm * 32 + mi * 16 + (lane >> 4) * 4;
      float bgv = bg[e], bvv = bv[e];
#pragma unroll
      for (int j = 0; j < 4; ++j) {
        float gp = accg[mi][ni][j] + bgv;
        float vp = accv[mi][ni][j] + bvv;
        float sg = 1.0f / (1.0f + __expf(-gp));
        float uu = (2.0f * sg - 1.0f) * vp;
        u[(rbase + j) * DD + e] = f2bf(uu);
      }
    }
}

// ---------------- kernel 4: per-chunk partial sums ----------------
// 128 threads/block, each block covers half of D for one (b,chunk).
__global__ __launch_bounds__(128) void scan_partial(
    const unsigned short* __restrict__ u, float* __restrict__ sums) {
  int bid = blockIdx.x;
  int half = bid & 1, chunk = (bid >> 1) & 63, b = bid >> 7;
  int e0 = half * 512 + threadIdx.x * 4;
  float a0 = 0.f, a1 = 0.f, a2 = 0.f, a3 = 0.f;
  size_t base = ((size_t)b * TT + (size_t)chunk * CLEN) * DD + e0;
#pragma unroll 4
  for (int i = 0; i < CLEN; ++i) {
    ushort4 w = *(const ushort4*)(u + base + (size_t)i * DD);
    a0 += bf2f(w.x); a1 += bf2f(w.y); a2 += bf2f(w.z); a3 += bf2f(w.w);
  }
  float4 rr; rr.x = a0; rr.y = a1; rr.z = a2; rr.w = a3;
  *(float4*)(sums + ((size_t)(b * NCHUNK + chunk)) * DD + e0) = rr;
}

// ---------------- kernel 5: exclusive scan over chunk sums (in place) ----------------
// Load all 64, prefix in registers, store all — one latency exposure.
__global__ __launch_bounds__(256) void scan_chunks(float* __restrict__ sums) {
  int b = blockIdx.x >> 2;
  int e = (blockIdx.x & 3) * 256 + threadIdx.x;
  float vals[NCHUNK];
#pragma unroll
  for (int c = 0; c < NCHUNK; ++c)
    vals[c] = sums[((size_t)(b * NCHUNK + c)) * DD + e];
  float carry = 0.f;
#pragma unroll
  for (int c = 0; c < NCHUNK; ++c) {
    float t = vals[c]; vals[c] = carry; carry += t;
  }
#pragma unroll
  for (int c = 0; c < NCHUNK; ++c)
    sums[((size_t)(b * NCHUNK + c)) * DD + e] = vals[c];
}

// ---------------- kernel 6: chunk-local scan + decay, in place ----------------
__global__ __launch_bounds__(128) void scan_final(
    unsigned short* __restrict__ u, const float* __restrict__ sums,
    const float* __restrict__ log_decay) {
  int bid = blockIdx.x;
  int half = bid & 1, chunk = (bid >> 1) & 63, b = bid >> 7;
  int e0 = half * 512 + threadIdx.x * 4;
  float alpha = log1pf(__expf(log_decay[0]));   // softplus
  float4 c = *(const float4*)(sums + ((size_t)(b * NCHUNK + chunk)) * DD + e0);
  size_t base = ((size_t)b * TT + (size_t)chunk * CLEN) * DD + e0;
#pragma unroll 4
  for (int i = 0; i < CLEN; ++i) {
    int t = chunk * CLEN + i;
    float dec = __expf(-alpha * (float)t);
    ushort4 w = *(const ushort4*)(u + base + (size_t)i * DD);
    c.x += bf2f(w.x); c.y += bf2f(w.y); c.z += bf2f(w.z); c.w += bf2f(w.w);
    ushort4 o;
    o.x = f2bf(c.x * dec); o.y = f2bf(c.y * dec);
    o.z = f2bf(c.z * dec); o.w = f2bf(c.w * dec);
    *(ushort4*)(u + base + (size_t)i * DD) = o;
  }
}

// ---------------- kernel 7: output GEMM + residual ----------------
// out[m,e] = x[m,e] + bo[e] + sum_d c[m,d]*Wo[e,d]   (m97 structure, 4 waves)
__global__ __launch_bounds__(256) void gemm_out(
    const unsigned short* __restrict__ cmat, const unsigned short* __restrict__ wo,
    const float* __restrict__ bo, const float* __restrict__ x,
    float* __restrict__ out) {
  __shared__ unsigned short As[128 * 32];
  __shared__ unsigned short Bs[128 * 32];
  int tid = threadIdx.x, lane = tid & 63, wid = tid >> 6;
  int wm = wid >> 1, wn = wid & 1;
  size_t m0 = (size_t)blockIdx.x * 128;
  int n0 = blockIdx.y * 128;

  f32x4 acc[4][4];
#pragma unroll
  for (int a = 0; a < 4; ++a)
#pragma unroll
    for (int b = 0; b < 4; ++b) acc[a][b] = (f32x4){0.f, 0.f, 0.f, 0.f};

  int r = lane & 15, kb = (lane >> 4) * 8;
  for (int kt = 0; kt < DD / 32; ++kt) {
    int k0 = kt * 32;
    stage256(cmat, m0, k0, As, tid);
    stage256(wo, (size_t)n0, k0, Bs, tid);
    __syncthreads();
    bf16x8 af[4];
#pragma unroll
    for (int mi = 0; mi < 4; ++mi)
      af[mi] = *(const bf16x8*)&As[(wm * 64 + mi * 16 + r) * 32 + kb];
#pragma unroll
    for (int ni = 0; ni < 4; ++ni) {
      bf16x8 bf = *(const bf16x8*)&Bs[(wn * 64 + ni * 16 + r) * 32 + kb];
#pragma unroll
      for (int mi = 0; mi < 4; ++mi)
        acc[mi][ni] = __builtin_amdgcn_mfma_f32_16x16x32_bf16(af[mi], bf, acc[mi][ni], 0, 0, 0);
    }
    __syncthreads();
  }

#pragma unroll
  for (int mi = 0; mi < 4; ++mi)
#pragma unroll
    for (int ni = 0; ni < 4; ++ni) {
      int e = n0 + wn * 64 + ni * 16 + (lane & 15);
      size_t rbase = m0 + wm * 64 + mi * 16 + (lane >> 4) * 4;
      float bov = bo[e];
#pragma unroll
      for (int j = 0; j < 4; ++j) {
        size_t idx = (rbase + j) * DD + e;
        out[idx] = x[idx] + bov + acc[mi][ni][j];
      }
    }
}

// ---------------- launch ----------------
extern "C" void kernel_launch(void* const* d_in, const int* in_sizes, int n_in,
                              void* d_out, int out_size, void* d_ws, size_t ws_size,
                              hipStream_t stream) {
  const float* x     = (const float*)d_in[0];
  const float* gamma = (const float*)d_in[1];
  const float* beta  = (const float*)d_in[2];
  const float* Wg    = (const float*)d_in[3];
  const float* bg    = (const float*)d_in[4];
  const float* Wv    = (const float*)d_in[5];
  const float* bv    = (const float*)d_in[6];
  const float* Wo    = (const float*)d_in[7];
  const float* bo    = (const float*)d_in[8];
  const float* ldcy  = (const float*)d_in[9];
  float* out = (float*)d_out;

  char* ws = (char*)d_ws;
  // layout: normed bf16 (64MiB) | u/c bf16 (64MiB) | Wg,Wv,Wo bf16 (3x2MiB) | sums f32 (1MiB)
  unsigned short* normed = (unsigned short*)ws;
  unsigned short* u      = (unsigned short*)(ws + (size_t)67108864);
  unsigned short* wgb    = (unsigned short*)(ws + (size_t)134217728);
  unsigned short* wvb    = wgb + 1048576;
  unsigned short* wob    = wvb + 1048576;
  float* sums            = (float*)(ws + (size_t)134217728 + (size_t)3 * 2097152);

  cast_weights<<<3072, 256, 0, stream>>>(Wg, Wv, Wo, wgb, wvb, wob);
  ln_kernel<<<MM, 256, 0, stream>>>(x, gamma, beta, normed);
  gemm_gv<<<dim3(MM / 128, DD / 128), 512, 0, stream>>>(normed, wgb, wvb, bg, bv, u);
  scan_partial<<<BB * NCHUNK * 2, 128, 0, stream>>>(u, sums);
  scan_chunks<<<BB * (DD / 256), 256, 0, stream>>>(sums);
  scan_final<<<BB * NCHUNK * 2, 128, 0, stream>>>(u, sums, ldcy);
  gemm_out<<<dim3(MM / 128, DD / 128), 256, 0, stream>>>(u, wob, bo, x, out);
}

// Round 3
// 387.109 us; speedup vs baseline: 1.5675x; 1.0986x over previous
//
#include <hip/hip_runtime.h>
#include <cstdint>
#include <cstddef>

// ---------------- problem constants ----------------
#define DD 1024          // feature dim (= K = N per GEMM)
#define TT 8192          // sequence length
#define BB 4             // batch
#define MM (BB*TT)       // 32768 rows
#define NCHUNK 64        // scan chunks over T
#define CLEN 128         // chunk length (NCHUNK*CLEN == TT)
#define EPS 1e-5f
#define NKT 32           // K tiles of 32 (DD/32)

typedef __attribute__((ext_vector_type(8))) short bf16x8;
typedef __attribute__((ext_vector_type(4))) float f32x4;

// ---------------- bf16 helpers (bit-level, RNE) ----------------
__device__ __forceinline__ float bf2f(unsigned short b) {
  union { unsigned int u; float f; } c; c.u = ((unsigned int)b) << 16; return c.f;
}
__device__ __forceinline__ unsigned short f2bf(float f) {
  union { float f; unsigned int u; } c; c.f = f;
  unsigned int lsb = (c.u >> 16) & 1u;
  c.u += 0x7fffu + lsb;
  return (unsigned short)(c.u >> 16);
}

// ---------------- async global->LDS (16B per lane) ----------------
__device__ __forceinline__ void gload16(const void* gsrc, void* ldst) {
  __builtin_amdgcn_global_load_lds(
      (const __attribute__((address_space(1))) unsigned int*)gsrc,
      (__attribute__((address_space(3))) unsigned int*)ldst, 16, 0, 0);
}

// LDS slot swizzle: row stride = 32 bf16 = 64B = 4 slots of 16B.
// phys_slot = log_slot ^ ((row>>1)&3)  (involution). Spreads a 16-lane frag
// read (rows r..r+15, fixed log slot) across all 8 bank-groups -> 2-way free.
#define SWZ(row) (((row) >> 1) & 3)

// Stage an R x 32 bf16 tile from row-major (ld=1024) global into LDS, with
// inverse-swizzled SOURCE (LDS dest stays linear per gload_lds constraint).
// R=256 -> 2 loads/thread, R=128 -> 1 load/thread (512 threads).
template<int R>
__device__ __forceinline__ void stageT(const unsigned short* __restrict__ g,
                                       size_t row0, int k0,
                                       unsigned short* lds, int tid) {
#pragma unroll
  for (int l = 0; l < R / 128; ++l) {
    int u16 = l * 512 + tid;          // 16B unit index in tile
    int row = u16 >> 2;
    int sp  = u16 & 3;                // physical slot
    int sl  = sp ^ SWZ(row);          // logical (global) slot
    const unsigned short* src = g + (row0 + (size_t)row) * DD + k0 + sl * 8;
    gload16(src, (char*)lds + (size_t)u16 * 16);
  }
}

// Read one MFMA A/B fragment (16 rows x 8 k) from a swizzled LDS tile.
__device__ __forceinline__ bf16x8 ldsfrag(const unsigned short* lds, int row, int sl) {
  int sp = sl ^ SWZ(row);
  return *(const bf16x8*)&lds[row * 32 + sp * 8];
}

// ---------------- barrier helpers (raw s_barrier, counted vmcnt) ----------------
__device__ __forceinline__ void phase_barrier() {
  __builtin_amdgcn_sched_barrier(0);
  __builtin_amdgcn_s_barrier();
  __builtin_amdgcn_sched_barrier(0);
}
template<int N>
__device__ __forceinline__ void tile_barrier_vm() {
  __builtin_amdgcn_sched_barrier(0);
  if constexpr (N == 4) asm volatile("s_waitcnt vmcnt(4)" ::: "memory");
  else                  asm volatile("s_waitcnt vmcnt(0)" ::: "memory");
  __builtin_amdgcn_s_barrier();
  __builtin_amdgcn_sched_barrier(0);
}

// ---------------- kernel 1: cast weights to bf16 ----------------
__global__ __launch_bounds__(256) void cast_weights(
    const float* __restrict__ wg, const float* __restrict__ wv,
    const float* __restrict__ wo,
    unsigned short* __restrict__ owg, unsigned short* __restrict__ owv,
    unsigned short* __restrict__ owo) {
  int i = blockIdx.x * 256 + threadIdx.x;   // over float4 units; 3*262144 total
  const float* src; unsigned short* dst; int off;
  if (i < 262144)       { src = wg; dst = owg; off = i; }
  else if (i < 524288)  { src = wv; dst = owv; off = i - 262144; }
  else                  { src = wo; dst = owo; off = i - 524288; }
  float4 v = ((const float4*)src)[off];
  ushort4 o;
  o.x = f2bf(v.x); o.y = f2bf(v.y); o.z = f2bf(v.z); o.w = f2bf(v.w);
  ((ushort4*)dst)[off] = o;
}

// ---------------- kernel 2: LayerNorm -> bf16 ----------------
__global__ __launch_bounds__(256) void ln_kernel(
    const float* __restrict__ x, const float* __restrict__ gamma,
    const float* __restrict__ beta, unsigned short* __restrict__ normed) {
  size_t row = blockIdx.x;
  int tid = threadIdx.x, lane = tid & 63, wid = tid >> 6;
  float4 v = ((const float4*)(x + row * DD))[tid];
  float s = v.x + v.y + v.z + v.w;
  float q = v.x * v.x + v.y * v.y + v.z * v.z + v.w * v.w;
#pragma unroll
  for (int off = 32; off; off >>= 1) {
    s += __shfl_down(s, off);
    q += __shfl_down(q, off);
  }
  __shared__ float rs[4], rq[4];
  if (lane == 0) { rs[wid] = s; rq[wid] = q; }
  __syncthreads();
  float ts = rs[0] + rs[1] + rs[2] + rs[3];
  float tq = rq[0] + rq[1] + rq[2] + rq[3];
  float mu  = ts * (1.0f / DD);
  float var = tq * (1.0f / DD) - mu * mu;
  float rstd = rsqrtf(var + EPS);
  float4 gm = ((const float4*)gamma)[tid];
  float4 bt = ((const float4*)beta)[tid];
  ushort4 o;
  o.x = f2bf((v.x - mu) * rstd * gm.x + bt.x);
  o.y = f2bf((v.y - mu) * rstd * gm.y + bt.y);
  o.z = f2bf((v.z - mu) * rstd * gm.z + bt.z);
  o.w = f2bf((v.w - mu) * rstd * gm.w + bt.w);
  ((ushort4*)normed)[row * (DD / 4) + tid] = o;
}

// ---------------- kernel 3: fused gate/value GEMM -> u ----------------
// 256x128 tile, 8 waves (4M x 2N), wave owns 64x64 of BOTH outputs.
// 4-deep LDS pipeline (stage t+2 during t), counted vmcnt(4), raw barriers,
// slot-swizzled LDS, setprio around MFMA clusters.
__global__ __launch_bounds__(512, 2) void gemm_gv(
    const unsigned short* __restrict__ normed,
    const unsigned short* __restrict__ wg, const unsigned short* __restrict__ wv,
    const float* __restrict__ bg, const float* __restrict__ bv,
    unsigned short* __restrict__ u) {
  __shared__ unsigned short As[4][256 * 32];   // 64 KiB
  __shared__ unsigned short Bgs[4][128 * 32];  // 32 KiB
  __shared__ unsigned short Bvs[4][128 * 32];  // 32 KiB
  int tid = threadIdx.x, lane = tid & 63, wid = tid >> 6;
  int wm = wid & 3, wn = wid >> 2;         // 4 M-groups x 2 N-groups
  int nwg = gridDim.x;                     // 1024, %8==0
  int swz = (blockIdx.x & 7) * (nwg >> 3) + (blockIdx.x >> 3);
  int bx = swz & 127;                      // M block (128 of them)
  int by = swz >> 7;                       // N block (8)
  size_t m0 = (size_t)bx * 256;
  int n0 = by * 128;

  f32x4 accg[4][4], accv[4][4];
#pragma unroll
  for (int a = 0; a < 4; ++a)
#pragma unroll
    for (int b = 0; b < 4; ++b) {
      accg[a][b] = (f32x4){0.f, 0.f, 0.f, 0.f};
      accv[a][b] = (f32x4){0.f, 0.f, 0.f, 0.f};
    }

  // prologue: stage tiles 0 and 1 (4 loads each), wait tile 0 (vmcnt(4))
  stageT<256>(normed, m0, 0, As[0], tid);
  stageT<128>(wg, (size_t)n0, 0, Bgs[0], tid);
  stageT<128>(wv, (size_t)n0, 0, Bvs[0], tid);
  stageT<256>(normed, m0, 32, As[1], tid);
  stageT<128>(wg, (size_t)n0, 32, Bgs[1], tid);
  stageT<128>(wv, (size_t)n0, 32, Bvs[1], tid);
  tile_barrier_vm<4>();

  int r = lane & 15, sl = lane >> 4;
  for (int kt = 0; kt < NKT; ++kt) {
    int buf = kt & 3;
    // ---- phase 0: A frags + Bg frags, compute accg ----
    bf16x8 af[4];
#pragma unroll
    for (int mi = 0; mi < 4; ++mi)
      af[mi] = ldsfrag(As[buf], wm * 64 + mi * 16 + r, sl);
    bf16x8 bgf[4];
#pragma unroll
    for (int ni = 0; ni < 4; ++ni)
      bgf[ni] = ldsfrag(Bgs[buf], wn * 64 + ni * 16 + r, sl);
    if (kt < NKT - 2)
      stageT<256>(normed, m0, (kt + 2) * 32, As[(kt + 2) & 3], tid);  // 2 loads
    phase_barrier();
    __builtin_amdgcn_s_setprio(1);
#pragma unroll
    for (int ni = 0; ni < 4; ++ni)
#pragma unroll
      for (int mi = 0; mi < 4; ++mi)
        accg[mi][ni] = __builtin_amdgcn_mfma_f32_16x16x32_bf16(af[mi], bgf[ni], accg[mi][ni], 0, 0, 0);
    __builtin_amdgcn_s_setprio(0);
    phase_barrier();
    // ---- phase 1: Bv frags, compute accv (A reused from regs) ----
    bf16x8 bvf[4];
#pragma unroll
    for (int ni = 0; ni < 4; ++ni)
      bvf[ni] = ldsfrag(Bvs[buf], wn * 64 + ni * 16 + r, sl);
    if (kt < NKT - 2) {
      stageT<128>(wg, (size_t)n0, (kt + 2) * 32, Bgs[(kt + 2) & 3], tid);  // 1 load
      stageT<128>(wv, (size_t)n0, (kt + 2) * 32, Bvs[(kt + 2) & 3], tid);  // 1 load
    }
    phase_barrier();
    __builtin_amdgcn_s_setprio(1);
#pragma unroll
    for (int ni = 0; ni < 4; ++ni)
#pragma unroll
      for (int mi = 0; mi < 4; ++mi)
        accv[mi][ni] = __builtin_amdgcn_mfma_f32_16x16x32_bf16(af[mi], bvf[ni], accv[mi][ni], 0, 0, 0);
    __builtin_amdgcn_s_setprio(0);
    // ---- tile boundary: counted wait (never 0 in steady state) ----
    if (kt < NKT - 2) tile_barrier_vm<4>();
    else              tile_barrier_vm<0>();
  }

  // epilogue: C/D layout col=lane&15, row=(lane>>4)*4+j  [m89/m91 verified]
#pragma unroll
  for (int mi = 0; mi < 4; ++mi)
#pragma unroll
    for (int ni = 0; ni < 4; ++ni) {
      int e = n0 + wn * 64 + ni * 16 + (lane & 15);
      size_t rbase = m0 + wm * 64 + mi * 16 + (lane >> 4) * 4;
      float bgv = bg[e], bvv = bv[e];
#pragma unroll
      for (int j = 0; j < 4; ++j) {
        float gp = accg[mi][ni][j] + bgv;
        float vp = accv[mi][ni][j] + bvv;
        float sg = 1.0f / (1.0f + __expf(-gp));
        float uu = (2.0f * sg - 1.0f) * vp;
        u[(rbase + j) * DD + e] = f2bf(uu);
      }
    }
}

// ---------------- kernel 4: per-chunk partial sums ----------------
__global__ __launch_bounds__(128) void scan_partial(
    const unsigned short* __restrict__ u, float* __restrict__ sums) {
  int bid = blockIdx.x;
  int half = bid & 1, chunk = (bid >> 1) & 63, b = bid >> 7;
  int e0 = half * 512 + threadIdx.x * 4;
  float a0 = 0.f, a1 = 0.f, a2 = 0.f, a3 = 0.f;
  size_t base = ((size_t)b * TT + (size_t)chunk * CLEN) * DD + e0;
#pragma unroll 4
  for (int i = 0; i < CLEN; ++i) {
    ushort4 w = *(const ushort4*)(u + base + (size_t)i * DD);
    a0 += bf2f(w.x); a1 += bf2f(w.y); a2 += bf2f(w.z); a3 += bf2f(w.w);
  }
  float4 rr; rr.x = a0; rr.y = a1; rr.z = a2; rr.w = a3;
  *(float4*)(sums + ((size_t)(b * NCHUNK + chunk)) * DD + e0) = rr;
}

// ---------------- kernel 5: exclusive scan over chunk sums (in place) ----------------
__global__ __launch_bounds__(256) void scan_chunks(float* __restrict__ sums) {
  int b = blockIdx.x >> 2;
  int e = (blockIdx.x & 3) * 256 + threadIdx.x;
  float vals[NCHUNK];
#pragma unroll
  for (int c = 0; c < NCHUNK; ++c)
    vals[c] = sums[((size_t)(b * NCHUNK + c)) * DD + e];
  float carry = 0.f;
#pragma unroll
  for (int c = 0; c < NCHUNK; ++c) {
    float t = vals[c]; vals[c] = carry; carry += t;
  }
#pragma unroll
  for (int c = 0; c < NCHUNK; ++c)
    sums[((size_t)(b * NCHUNK + c)) * DD + e] = vals[c];
}

// ---------------- kernel 6: chunk-local scan + decay, in place ----------------
__global__ __launch_bounds__(128) void scan_final(
    unsigned short* __restrict__ u, const float* __restrict__ sums,
    const float* __restrict__ log_decay) {
  int bid = blockIdx.x;
  int half = bid & 1, chunk = (bid >> 1) & 63, b = bid >> 7;
  int e0 = half * 512 + threadIdx.x * 4;
  float alpha = log1pf(__expf(log_decay[0]));   // softplus
  float4 c = *(const float4*)(sums + ((size_t)(b * NCHUNK + chunk)) * DD + e0);
  size_t base = ((size_t)b * TT + (size_t)chunk * CLEN) * DD + e0;
#pragma unroll 4
  for (int i = 0; i < CLEN; ++i) {
    int t = chunk * CLEN + i;
    float dec = __expf(-alpha * (float)t);
    ushort4 w = *(const ushort4*)(u + base + (size_t)i * DD);
    c.x += bf2f(w.x); c.y += bf2f(w.y); c.z += bf2f(w.z); c.w += bf2f(w.w);
    ushort4 o;
    o.x = f2bf(c.x * dec); o.y = f2bf(c.y * dec);
    o.z = f2bf(c.z * dec); o.w = f2bf(c.w * dec);
    *(ushort4*)(u + base + (size_t)i * DD) = o;
  }
}

// ---------------- kernel 7: output GEMM + residual ----------------
// 256x256 tile, 8 waves (2M x 4N), wave owns 128x64. Same pipeline as gemm_gv.
// out[m,e] = x[m,e] + bo[e] + sum_d c[m,d]*Wo[e,d]
__global__ __launch_bounds__(512, 2) void gemm_out(
    const unsigned short* __restrict__ cmat, const unsigned short* __restrict__ wo,
    const float* __restrict__ bo, const float* __restrict__ x,
    float* __restrict__ out) {
  __shared__ unsigned short As[4][256 * 32];   // 64 KiB
  __shared__ unsigned short Bs[4][256 * 32];   // 64 KiB
  int tid = threadIdx.x, lane = tid & 63, wid = tid >> 6;
  int wm = wid & 1, wn = wid >> 1;         // 2 M-groups x 4 N-groups
  int nwg = gridDim.x;                     // 512, %8==0
  int swz = (blockIdx.x & 7) * (nwg >> 3) + (blockIdx.x >> 3);
  int bx = swz & 127;                      // M block (128)
  int by = swz >> 7;                       // N block (4)
  size_t m0 = (size_t)bx * 256;
  int n0 = by * 256;

  f32x4 acc[8][4];
#pragma unroll
  for (int a = 0; a < 8; ++a)
#pragma unroll
    for (int b = 0; b < 4; ++b) acc[a][b] = (f32x4){0.f, 0.f, 0.f, 0.f};

  stageT<256>(cmat, m0, 0, As[0], tid);
  stageT<256>(wo, (size_t)n0, 0, Bs[0], tid);
  stageT<256>(cmat, m0, 32, As[1], tid);
  stageT<256>(wo, (size_t)n0, 32, Bs[1], tid);
  tile_barrier_vm<4>();

  int r = lane & 15, sl = lane >> 4;
  for (int kt = 0; kt < NKT; ++kt) {
    int buf = kt & 3;
    // ---- phase 0: A frags (all 8 M) + B frags n0,n1 ----
    bf16x8 af[8];
#pragma unroll
    for (int mi = 0; mi < 8; ++mi)
      af[mi] = ldsfrag(As[buf], wm * 128 + mi * 16 + r, sl);
    bf16x8 b0 = ldsfrag(Bs[buf], wn * 64 + 0 * 16 + r, sl);
    bf16x8 b1 = ldsfrag(Bs[buf], wn * 64 + 1 * 16 + r, sl);
    if (kt < NKT - 2)
      stageT<256>(cmat, m0, (kt + 2) * 32, As[(kt + 2) & 3], tid);  // 2 loads
    phase_barrier();
    __builtin_amdgcn_s_setprio(1);
#pragma unroll
    for (int mi = 0; mi < 8; ++mi) {
      acc[mi][0] = __builtin_amdgcn_mfma_f32_16x16x32_bf16(af[mi], b0, acc[mi][0], 0, 0, 0);
      acc[mi][1] = __builtin_amdgcn_mfma_f32_16x16x32_bf16(af[mi], b1, acc[mi][1], 0, 0, 0);
    }
    __builtin_amdgcn_s_setprio(0);
    phase_barrier();
    // ---- phase 1: B frags n2,n3 (A reused) ----
    bf16x8 b2 = ldsfrag(Bs[buf], wn * 64 + 2 * 16 + r, sl);
    bf16x8 b3 = ldsfrag(Bs[buf], wn * 64 + 3 * 16 + r, sl);
    if (kt < NKT - 2)
      stageT<256>(wo, (size_t)n0, (kt + 2) * 32, Bs[(kt + 2) & 3], tid);  // 2 loads
    phase_barrier();
    __builtin_amdgcn_s_setprio(1);
#pragma unroll
    for (int mi = 0; mi < 8; ++mi) {
      acc[mi][2] = __builtin_amdgcn_mfma_f32_16x16x32_bf16(af[mi], b2, acc[mi][2], 0, 0, 0);
      acc[mi][3] = __builtin_amdgcn_mfma_f32_16x16x32_bf16(af[mi], b3, acc[mi][3], 0, 0, 0);
    }
    __builtin_amdgcn_s_setprio(0);
    if (kt < NKT - 2) tile_barrier_vm<4>();
    else              tile_barrier_vm<0>();
  }

#pragma unroll
  for (int mi = 0; mi < 8; ++mi)
#pragma unroll
    for (int ni = 0; ni < 4; ++ni) {
      int e = n0 + wn * 64 + ni * 16 + (lane & 15);
      size_t rbase = m0 + wm * 128 + mi * 16 + (lane >> 4) * 4;
      float bov = bo[e];
#pragma unroll
      for (int j = 0; j < 4; ++j) {
        size_t idx = (rbase + j) * DD + e;
        out[idx] = x[idx] + bov + acc[mi][ni][j];
      }
    }
}

// ---------------- launch ----------------
extern "C" void kernel_launch(void* const* d_in, const int* in_sizes, int n_in,
                              void* d_out, int out_size, void* d_ws, size_t ws_size,
                              hipStream_t stream) {
  const float* x     = (const float*)d_in[0];
  const float* gamma = (const float*)d_in[1];
  const float* beta  = (const float*)d_in[2];
  const float* Wg    = (const float*)d_in[3];
  const float* bg    = (const float*)d_in[4];
  const float* Wv    = (const float*)d_in[5];
  const float* bv    = (const float*)d_in[6];
  const float* Wo    = (const float*)d_in[7];
  const float* bo    = (const float*)d_in[8];
  const float* ldcy  = (const float*)d_in[9];
  float* out = (float*)d_out;

  char* ws = (char*)d_ws;
  // layout: normed bf16 (64MiB) | u/c bf16 (64MiB) | Wg,Wv,Wo bf16 (3x2MiB) | sums f32 (1MiB)
  unsigned short* normed = (unsigned short*)ws;
  unsigned short* u      = (unsigned short*)(ws + (size_t)67108864);
  unsigned short* wgb    = (unsigned short*)(ws + (size_t)134217728);
  unsigned short* wvb    = wgb + 1048576;
  unsigned short* wob    = wvb + 1048576;
  float* sums            = (float*)(ws + (size_t)134217728 + (size_t)3 * 2097152);

  cast_weights<<<3072, 256, 0, stream>>>(Wg, Wv, Wo, wgb, wvb, wob);
  ln_kernel<<<MM, 256, 0, stream>>>(x, gamma, beta, normed);
  gemm_gv<<<dim3(MM / 256 * (DD / 128)), 512, 0, stream>>>(normed, wgb, wvb, bg, bv, u);
  scan_partial<<<BB * NCHUNK * 2, 128, 0, stream>>>(u, sums);
  scan_chunks<<<BB * (DD / 256), 256, 0, stream>>>(sums);
  scan_final<<<BB * NCHUNK * 2, 128, 0, stream>>>(u, sums, ldcy);
  gemm_out<<<dim3(MM / 256 * (DD / 256)), 512, 0, stream>>>(u, wob, bo, x, out);
}

// Round 4
// 328.294 us; speedup vs baseline: 1.8484x; 1.1792x over previous
//
#include <hip/hip_runtime.h>
#include <cstdint>
#include <cstddef>

// ---------------- problem constants ----------------
#define DD 1024          // feature dim (= K = N per GEMM)
#define TT 8192          // sequence length
#define BB 4             // batch
#define MM (BB*TT)       // 32768 rows
#define NCHUNK 64        // scan chunks over T
#define CLEN 128         // chunk length (NCHUNK*CLEN == TT)
#define EPS 1e-5f
#define NK2 16           // K tiles of 64 (DD/64)

typedef __attribute__((ext_vector_type(8))) short bf16x8;
typedef __attribute__((ext_vector_type(4))) float f32x4;

// ---------------- bf16 helpers (bit-level, RNE) ----------------
__device__ __forceinline__ float bf2f(unsigned short b) {
  union { unsigned int u; float f; } c; c.u = ((unsigned int)b) << 16; return c.f;
}
__device__ __forceinline__ unsigned short f2bf(float f) {
  union { float f; unsigned int u; } c; c.f = f;
  unsigned int lsb = (c.u >> 16) & 1u;
  c.u += 0x7fffu + lsb;
  return (unsigned short)(c.u >> 16);
}

// ---------------- async global->LDS (16B per lane) ----------------
__device__ __forceinline__ void gload16(const void* gsrc, void* ldst) {
  __builtin_amdgcn_global_load_lds(
      (const __attribute__((address_space(1))) unsigned int*)gsrc,
      (__attribute__((address_space(3))) unsigned int*)ldst, 16, 0, 0);
}

// LDS slot swizzle over [R][32]-packed k-half tiles: row = 64B = 4 slots of
// 16B; phys_slot = log_slot ^ ((row>>1)&3). Verified 0 bank conflicts (R3).
#define SWZ(row) (((row) >> 1) & 3)

// Stage an R x 32 bf16 k-half from row-major (ld=1024) global into LDS,
// inverse-swizzled SOURCE (LDS dest linear per gload_lds constraint).
// R=256 -> 2 instr/wave, R=128 -> 1 instr/wave (512 threads).
template<int R>
__device__ __forceinline__ void stageT(const unsigned short* __restrict__ g,
                                       size_t row0, int k0,
                                       unsigned short* lds, int tid) {
#pragma unroll
  for (int l = 0; l < R / 128; ++l) {
    int u16 = l * 512 + tid;          // 16B unit index in tile
    int row = u16 >> 2;
    int sp  = u16 & 3;                // physical slot
    int sl  = sp ^ SWZ(row);          // logical (global) slot
    const unsigned short* src = g + (row0 + (size_t)row) * DD + k0 + sl * 8;
    gload16(src, (char*)lds + (size_t)u16 * 16);
  }
}

// Read one MFMA A/B fragment (16 rows x 8 k) from a swizzled k-half tile.
__device__ __forceinline__ bf16x8 ldsfrag(const unsigned short* lds, int row, int sl) {
  int sp = sl ^ SWZ(row);
  return *(const bf16x8*)&lds[row * 32 + sp * 8];
}

#define MFMA16(a, b, c) __builtin_amdgcn_mfma_f32_16x16x32_bf16((a), (b), (c), 0, 0, 0)

__device__ __forceinline__ void lgkm0_fence() {
  asm volatile("s_waitcnt lgkmcnt(0)" ::: "memory");
  __builtin_amdgcn_sched_barrier(0);   // rule #18
}

// ---------------- kernel 1: cast weights to bf16 ----------------
__global__ __launch_bounds__(256) void cast_weights(
    const float* __restrict__ wg, const float* __restrict__ wv,
    const float* __restrict__ wo,
    unsigned short* __restrict__ owg, unsigned short* __restrict__ owv,
    unsigned short* __restrict__ owo) {
  int i = blockIdx.x * 256 + threadIdx.x;   // over float4 units; 3*262144 total
  const float* src; unsigned short* dst; int off;
  if (i < 262144)       { src = wg; dst = owg; off = i; }
  else if (i < 524288)  { src = wv; dst = owv; off = i - 262144; }
  else                  { src = wo; dst = owo; off = i - 524288; }
  float4 v = ((const float4*)src)[off];
  ushort4 o;
  o.x = f2bf(v.x); o.y = f2bf(v.y); o.z = f2bf(v.z); o.w = f2bf(v.w);
  ((ushort4*)dst)[off] = o;
}

// ---------------- kernel 2: LayerNorm -> bf16 ----------------
__global__ __launch_bounds__(256) void ln_kernel(
    const float* __restrict__ x, const float* __restrict__ gamma,
    const float* __restrict__ beta, unsigned short* __restrict__ normed) {
  size_t row = blockIdx.x;
  int tid = threadIdx.x, lane = tid & 63, wid = tid >> 6;
  float4 v = ((const float4*)(x + row * DD))[tid];
  float s = v.x + v.y + v.z + v.w;
  float q = v.x * v.x + v.y * v.y + v.z * v.z + v.w * v.w;
#pragma unroll
  for (int off = 32; off; off >>= 1) {
    s += __shfl_down(s, off);
    q += __shfl_down(q, off);
  }
  __shared__ float rs[4], rq[4];
  if (lane == 0) { rs[wid] = s; rq[wid] = q; }
  __syncthreads();
  float ts = rs[0] + rs[1] + rs[2] + rs[3];
  float tq = rq[0] + rq[1] + rq[2] + rq[3];
  float mu  = ts * (1.0f / DD);
  float var = tq * (1.0f / DD) - mu * mu;
  float rstd = rsqrtf(var + EPS);
  float4 gm = ((const float4*)gamma)[tid];
  float4 bt = ((const float4*)beta)[tid];
  ushort4 o;
  o.x = f2bf((v.x - mu) * rstd * gm.x + bt.x);
  o.y = f2bf((v.y - mu) * rstd * gm.y + bt.y);
  o.z = f2bf((v.z - mu) * rstd * gm.z + bt.z);
  o.w = f2bf((v.w - mu) * rstd * gm.w + bt.w);
  ((ushort4*)normed)[row * (DD / 4) + tid] = o;
}

// ---------------- kernel 3: fused gate/value GEMM -> u (+ chunk sums) ------
// 256x128 tile, BK=64, 8 waves (2M x 4N), wave owns 128x32 of BOTH outputs.
// k-half 4-phase schedule, counted vmcnt(4) at ends of p1/p3, raw barriers.
// u[m,e] = (2*sigmoid(normed@Wg^T+bg)-1) * (normed@Wv^T+bv); also emits
// per-(chunk,e) partial sums (block exclusively owns 2 chunks x 128 cols).
__global__ __launch_bounds__(512, 2) void gemm_gv(
    const unsigned short* __restrict__ normed,
    const unsigned short* __restrict__ wg, const unsigned short* __restrict__ wv,
    const float* __restrict__ bg, const float* __restrict__ bv,
    unsigned short* __restrict__ u, float* __restrict__ sums) {
  __shared__ unsigned short As[2][2][256 * 32];   // [buf][khalf] 64 KiB
  __shared__ unsigned short Bgs[2][2][128 * 32];  // 32 KiB
  __shared__ unsigned short Bvs[2][2][128 * 32];  // 32 KiB
  int tid = threadIdx.x, lane = tid & 63, wid = tid >> 6;
  int wm = wid >> 2, wn = wid & 3;         // 2 M-groups x 4 N-groups
  int nwg = gridDim.x;                     // 1024, %8==0
  int swz = (blockIdx.x & 7) * (nwg >> 3) + (blockIdx.x >> 3);
  int bx = swz >> 3;                       // M block (128); by fastest ->
  int by = swz & 7;                        // each XCD owns a contiguous bx chunk
  size_t m0 = (size_t)bx * 256;
  int n0 = by * 128;

  f32x4 accg[8][2], accv[8][2];
#pragma unroll
  for (int a = 0; a < 8; ++a)
#pragma unroll
    for (int b = 0; b < 2; ++b) {
      accg[a][b] = (f32x4){0.f, 0.f, 0.f, 0.f};
      accv[a][b] = (f32x4){0.f, 0.f, 0.f, 0.f};
    }

  // prologue: stage tile 0 (order A0, Bg0, Bv0, A1, Bg1, Bv1 = 8 instr/wave)
  stageT<256>(normed, m0, 0,  As[0][0], tid);
  stageT<128>(wg, (size_t)n0, 0,  Bgs[0][0], tid);
  stageT<128>(wv, (size_t)n0, 0,  Bvs[0][0], tid);
  stageT<256>(normed, m0, 32, As[0][1], tid);
  stageT<128>(wg, (size_t)n0, 32, Bgs[0][1], tid);
  stageT<128>(wv, (size_t)n0, 32, Bvs[0][1], tid);
  asm volatile("s_waitcnt vmcnt(4)" ::: "memory");   // A0,Bg0,Bv0 landed
  __builtin_amdgcn_s_barrier();

  int r = lane & 15, q = lane >> 4;
  for (int t = 0; t < NK2; ++t) {
    int buf = t & 1;
    int k1 = (t + 1) * 64;
    bool more = (t + 1 < NK2);
    bf16x8 af[8], b0, b1;
    // ---- p0: kk0, gate ----
#pragma unroll
    for (int mi = 0; mi < 8; ++mi)
      af[mi] = ldsfrag(As[buf][0], wm * 128 + mi * 16 + r, q);
    b0 = ldsfrag(Bgs[buf][0], wn * 32 + r, q);
    b1 = ldsfrag(Bgs[buf][0], wn * 32 + 16 + r, q);
    if (more) stageT<256>(normed, m0, k1, As[buf ^ 1][0], tid);
    __builtin_amdgcn_s_barrier();
    lgkm0_fence();
    __builtin_amdgcn_s_setprio(1);
#pragma unroll
    for (int mi = 0; mi < 8; ++mi) {
      accg[mi][0] = MFMA16(af[mi], b0, accg[mi][0]);
      accg[mi][1] = MFMA16(af[mi], b1, accg[mi][1]);
    }
    __builtin_amdgcn_s_setprio(0);
    __builtin_amdgcn_s_barrier();
    // ---- p1: kk0, value ----
    b0 = ldsfrag(Bvs[buf][0], wn * 32 + r, q);
    b1 = ldsfrag(Bvs[buf][0], wn * 32 + 16 + r, q);
    if (more) {
      stageT<128>(wg, (size_t)n0, k1, Bgs[buf ^ 1][0], tid);
      stageT<128>(wv, (size_t)n0, k1, Bvs[buf ^ 1][0], tid);
    }
    __builtin_amdgcn_s_barrier();
    lgkm0_fence();
    __builtin_amdgcn_s_setprio(1);
#pragma unroll
    for (int mi = 0; mi < 8; ++mi) {
      accv[mi][0] = MFMA16(af[mi], b0, accv[mi][0]);
      accv[mi][1] = MFMA16(af[mi], b1, accv[mi][1]);
    }
    __builtin_amdgcn_s_setprio(0);
    if (more) asm volatile("s_waitcnt vmcnt(4)" ::: "memory");  // A1,Bg1,Bv1(t)
    else      asm volatile("s_waitcnt vmcnt(0)" ::: "memory");
    __builtin_amdgcn_s_barrier();
    // ---- p2: kk1, value ----
#pragma unroll
    for (int mi = 0; mi < 8; ++mi)
      af[mi] = ldsfrag(As[buf][1], wm * 128 + mi * 16 + r, q);
    b0 = ldsfrag(Bvs[buf][1], wn * 32 + r, q);
    b1 = ldsfrag(Bvs[buf][1], wn * 32 + 16 + r, q);
    if (more) stageT<256>(normed, m0, k1 + 32, As[buf ^ 1][1], tid);
    __builtin_amdgcn_s_barrier();
    lgkm0_fence();
    __builtin_amdgcn_s_setprio(1);
#pragma unroll
    for (int mi = 0; mi < 8; ++mi) {
      accv[mi][0] = MFMA16(af[mi], b0, accv[mi][0]);
      accv[mi][1] = MFMA16(af[mi], b1, accv[mi][1]);
    }
    __builtin_amdgcn_s_setprio(0);
    __builtin_amdgcn_s_barrier();
    // ---- p3: kk1, gate ----
    b0 = ldsfrag(Bgs[buf][1], wn * 32 + r, q);
    b1 = ldsfrag(Bgs[buf][1], wn * 32 + 16 + r, q);
    if (more) {
      stageT<128>(wg, (size_t)n0, k1 + 32, Bgs[buf ^ 1][1], tid);
      stageT<128>(wv, (size_t)n0, k1 + 32, Bvs[buf ^ 1][1], tid);
    }
    __builtin_amdgcn_s_barrier();
    lgkm0_fence();
    __builtin_amdgcn_s_setprio(1);
#pragma unroll
    for (int mi = 0; mi < 8; ++mi) {
      accg[mi][0] = MFMA16(af[mi], b0, accg[mi][0]);
      accg[mi][1] = MFMA16(af[mi], b1, accg[mi][1]);
    }
    __builtin_amdgcn_s_setprio(0);
    if (more) asm volatile("s_waitcnt vmcnt(4)" ::: "memory");  // A0,Bg0,Bv0(t+1)
    __builtin_amdgcn_s_barrier();
  }

  // epilogue: u = (2*sigmoid(g)-1)*v, plus fused per-chunk partial sums.
  // C/D layout col=lane&15, row=(lane>>4)*4+j  [m89/m91 verified]
  float psum[2] = {0.f, 0.f};
#pragma unroll
  for (int mi = 0; mi < 8; ++mi)
#pragma unroll
    for (int ni = 0; ni < 2; ++ni) {
      int e = n0 + wn * 32 + ni * 16 + r;
      size_t rbase = m0 + wm * 128 + mi * 16 + q * 4;
      float bgv = bg[e], bvv = bv[e];
#pragma unroll
      for (int j = 0; j < 4; ++j) {
        float gp = accg[mi][ni][j] + bgv;
        float vp = accv[mi][ni][j] + bvv;
        float sg = 1.0f / (1.0f + __expf(-gp));
        float uu = (2.0f * sg - 1.0f) * vp;
        psum[ni] += uu;
        u[(rbase + j) * DD + e] = f2bf(uu);
      }
    }
  // reduce over the 4 row-subgroups (lane ^16, ^32); chunk = 128 rows = wave wm
#pragma unroll
  for (int ni = 0; ni < 2; ++ni) {
    psum[ni] += __shfl_xor(psum[ni], 16);
    psum[ni] += __shfl_xor(psum[ni], 32);
  }
  if (lane < 16) {
    int b = (int)(m0 >> 13);
    int ch = (int)((m0 & 8191) >> 7) + wm;
    size_t sidx = ((size_t)(b * NCHUNK + ch)) * DD + n0 + wn * 32 + lane;
    sums[sidx]      = psum[0];
    sums[sidx + 16] = psum[1];
  }
}

// ---------------- kernel 5: exclusive scan over chunk sums (in place) ------
__global__ __launch_bounds__(256) void scan_chunks(float* __restrict__ sums) {
  int b = blockIdx.x >> 2;
  int e = (blockIdx.x & 3) * 256 + threadIdx.x;
  float vals[NCHUNK];
#pragma unroll
  for (int c = 0; c < NCHUNK; ++c)
    vals[c] = sums[((size_t)(b * NCHUNK + c)) * DD + e];
  float carry = 0.f;
#pragma unroll
  for (int c = 0; c < NCHUNK; ++c) {
    float t = vals[c]; vals[c] = carry; carry += t;
  }
#pragma unroll
  for (int c = 0; c < NCHUNK; ++c)
    sums[((size_t)(b * NCHUNK + c)) * DD + e] = vals[c];
}

// ---------------- kernel 6: chunk-local scan + decay, in place ----------------
__global__ __launch_bounds__(128) void scan_final(
    unsigned short* __restrict__ u, const float* __restrict__ sums,
    const float* __restrict__ log_decay) {
  int bid = blockIdx.x;
  int half = bid & 1, chunk = (bid >> 1) & 63, b = bid >> 7;
  int e0 = half * 512 + threadIdx.x * 4;
  float alpha = log1pf(__expf(log_decay[0]));   // softplus
  float4 c = *(const float4*)(sums + ((size_t)(b * NCHUNK + chunk)) * DD + e0);
  size_t base = ((size_t)b * TT + (size_t)chunk * CLEN) * DD + e0;
#pragma unroll 4
  for (int i = 0; i < CLEN; ++i) {
    int t = chunk * CLEN + i;
    float dec = __expf(-alpha * (float)t);
    ushort4 w = *(const ushort4*)(u + base + (size_t)i * DD);
    c.x += bf2f(w.x); c.y += bf2f(w.y); c.z += bf2f(w.z); c.w += bf2f(w.w);
    ushort4 o;
    o.x = f2bf(c.x * dec); o.y = f2bf(c.y * dec);
    o.z = f2bf(c.z * dec); o.w = f2bf(c.w * dec);
    *(ushort4*)(u + base + (size_t)i * DD) = o;
  }
}

// ---------------- kernel 7: output GEMM + residual ----------------
// 256x256 tile, BK=64, 8 waves (2M x 4N), wave owns 128x64.
// Same k-half 4-phase schedule as gemm_gv.
// out[m,e] = x[m,e] + bo[e] + sum_d c[m,d]*Wo[e,d]
__global__ __launch_bounds__(512, 2) void gemm_out(
    const unsigned short* __restrict__ cmat, const unsigned short* __restrict__ wo,
    const float* __restrict__ bo, const float* __restrict__ x,
    float* __restrict__ out) {
  __shared__ unsigned short As[2][2][256 * 32];   // 64 KiB
  __shared__ unsigned short Bs[2][2][256 * 32];   // 64 KiB
  int tid = threadIdx.x, lane = tid & 63, wid = tid >> 6;
  int wm = wid >> 2, wn = wid & 3;         // 2 M-groups x 4 N-groups
  int nwg = gridDim.x;                     // 512, %8==0
  int swz = (blockIdx.x & 7) * (nwg >> 3) + (blockIdx.x >> 3);
  int bx = swz >> 2;                       // M block (128); by fastest
  int by = swz & 3;                        // N block (4)
  size_t m0 = (size_t)bx * 256;
  int n0 = by * 256;

  f32x4 acc[8][4];
#pragma unroll
  for (int a = 0; a < 8; ++a)
#pragma unroll
    for (int b = 0; b < 4; ++b) acc[a][b] = (f32x4){0.f, 0.f, 0.f, 0.f};

  // prologue: stage tile 0 (order A0, B0, A1, B1 = 8 instr/wave)
  stageT<256>(cmat, m0, 0,  As[0][0], tid);
  stageT<256>(wo, (size_t)n0, 0,  Bs[0][0], tid);
  stageT<256>(cmat, m0, 32, As[0][1], tid);
  stageT<256>(wo, (size_t)n0, 32, Bs[0][1], tid);
  asm volatile("s_waitcnt vmcnt(4)" ::: "memory");   // A0,B0 landed
  __builtin_amdgcn_s_barrier();

  int r = lane & 15, q = lane >> 4;
  for (int t = 0; t < NK2; ++t) {
    int buf = t & 1;
    int k1 = (t + 1) * 64;
    bool more = (t + 1 < NK2);
    bf16x8 af[8], b0, b1;
    // ---- p0: kk0, nh0 ----
#pragma unroll
    for (int mi = 0; mi < 8; ++mi)
      af[mi] = ldsfrag(As[buf][0], wm * 128 + mi * 16 + r, q);
    b0 = ldsfrag(Bs[buf][0], wn * 64 + r, q);
    b1 = ldsfrag(Bs[buf][0], wn * 64 + 16 + r, q);
    if (more) stageT<256>(cmat, m0, k1, As[buf ^ 1][0], tid);
    __builtin_amdgcn_s_barrier();
    lgkm0_fence();
    __builtin_amdgcn_s_setprio(1);
#pragma unroll
    for (int mi = 0; mi < 8; ++mi) {
      acc[mi][0] = MFMA16(af[mi], b0, acc[mi][0]);
      acc[mi][1] = MFMA16(af[mi], b1, acc[mi][1]);
    }
    __builtin_amdgcn_s_setprio(0);
    __builtin_amdgcn_s_barrier();
    // ---- p1: kk0, nh1 ----
    b0 = ldsfrag(Bs[buf][0], wn * 64 + 32 + r, q);
    b1 = ldsfrag(Bs[buf][0], wn * 64 + 48 + r, q);
    if (more) stageT<256>(wo, (size_t)n0, k1, Bs[buf ^ 1][0], tid);
    __builtin_amdgcn_s_barrier();
    lgkm0_fence();
    __builtin_amdgcn_s_setprio(1);
#pragma unroll
    for (int mi = 0; mi < 8; ++mi) {
      acc[mi][2] = MFMA16(af[mi], b0, acc[mi][2]);
      acc[mi][3] = MFMA16(af[mi], b1, acc[mi][3]);
    }
    __builtin_amdgcn_s_setprio(0);
    if (more) asm volatile("s_waitcnt vmcnt(4)" ::: "memory");  // A1,B1(t)
    else      asm volatile("s_waitcnt vmcnt(0)" ::: "memory");
    __builtin_amdgcn_s_barrier();
    // ---- p2: kk1, nh1 ----
#pragma unroll
    for (int mi = 0; mi < 8; ++mi)
      af[mi] = ldsfrag(As[buf][1], wm * 128 + mi * 16 + r, q);
    b0 = ldsfrag(Bs[buf][1], wn * 64 + 32 + r, q);
    b1 = ldsfrag(Bs[buf][1], wn * 64 + 48 + r, q);
    if (more) stageT<256>(cmat, m0, k1 + 32, As[buf ^ 1][1], tid);
    __builtin_amdgcn_s_barrier();
    lgkm0_fence();
    __builtin_amdgcn_s_setprio(1);
#pragma unroll
    for (int mi = 0; mi < 8; ++mi) {
      acc[mi][2] = MFMA16(af[mi], b0, acc[mi][2]);
      acc[mi][3] = MFMA16(af[mi], b1, acc[mi][3]);
    }
    __builtin_amdgcn_s_setprio(0);
    __builtin_amdgcn_s_barrier();
    // ---- p3: kk1, nh0 ----
    b0 = ldsfrag(Bs[buf][1], wn * 64 + r, q);
    b1 = ldsfrag(Bs[buf][1], wn * 64 + 16 + r, q);
    if (more) stageT<256>(wo, (size_t)n0, k1 + 32, Bs[buf ^ 1][1], tid);
    __builtin_amdgcn_s_barrier();
    lgkm0_fence();
    __builtin_amdgcn_s_setprio(1);
#pragma unroll
    for (int mi = 0; mi < 8; ++mi) {
      acc[mi][0] = MFMA16(af[mi], b0, acc[mi][0]);
      acc[mi][1] = MFMA16(af[mi], b1, acc[mi][1]);
    }
    __builtin_amdgcn_s_setprio(0);
    if (more) asm volatile("s_waitcnt vmcnt(4)" ::: "memory");  // A0,B0(t+1)
    __builtin_amdgcn_s_barrier();
  }

#pragma unroll
  for (int mi = 0; mi < 8; ++mi)
#pragma unroll
    for (int nq = 0; nq < 4; ++nq) {
      int e = n0 + wn * 64 + nq * 16 + r;
      size_t rbase = m0 + wm * 128 + mi * 16 + q * 4;
      float bov = bo[e];
#pragma unroll
      for (int j = 0; j < 4; ++j) {
        size_t idx = (rbase + j) * DD + e;
        out[idx] = x[idx] + bov + acc[mi][nq][j];
      }
    }
}

// ---------------- launch ----------------
extern "C" void kernel_launch(void* const* d_in, const int* in_sizes, int n_in,
                              void* d_out, int out_size, void* d_ws, size_t ws_size,
                              hipStream_t stream) {
  const float* x     = (const float*)d_in[0];
  const float* gamma = (const float*)d_in[1];
  const float* beta  = (const float*)d_in[2];
  const float* Wg    = (const float*)d_in[3];
  const float* bg    = (const float*)d_in[4];
  const float* Wv    = (const float*)d_in[5];
  const float* bv    = (const float*)d_in[6];
  const float* Wo    = (const float*)d_in[7];
  const float* bo    = (const float*)d_in[8];
  const float* ldcy  = (const float*)d_in[9];
  float* out = (float*)d_out;

  char* ws = (char*)d_ws;
  // layout: normed bf16 (64MiB) | u/c bf16 (64MiB) | Wg,Wv,Wo bf16 (3x2MiB) | sums f32 (1MiB)
  unsigned short* normed = (unsigned short*)ws;
  unsigned short* u      = (unsigned short*)(ws + (size_t)67108864);
  unsigned short* wgb    = (unsigned short*)(ws + (size_t)134217728);
  unsigned short* wvb    = wgb + 1048576;
  unsigned short* wob    = wvb + 1048576;
  float* sums            = (float*)(ws + (size_t)134217728 + (size_t)3 * 2097152);

  cast_weights<<<3072, 256, 0, stream>>>(Wg, Wv, Wo, wgb, wvb, wob);
  ln_kernel<<<MM, 256, 0, stream>>>(x, gamma, beta, normed);
  gemm_gv<<<dim3(MM / 256 * (DD / 128)), 512, 0, stream>>>(normed, wgb, wvb, bg, bv, u, sums);
  scan_chunks<<<BB * (DD / 256), 256, 0, stream>>>(sums);
  scan_final<<<BB * NCHUNK * 2, 128, 0, stream>>>(u, sums, ldcy);
  gemm_out<<<dim3(MM / 256 * (DD / 256)), 512, 0, stream>>>(u, wob, bo, x, out);
}